// Round 5
// baseline (957.366 us; speedup 1.0000x reference)
//
#include <hip/hip_runtime.h>

// TinyLSTM: I=128, H=64, C=10, B=256, T=1024
// Round 5:
//   Phase 1 (xproj2): registered-B MFMA GEMM, no LDS, no barriers. Each wave
//     holds 16 B-frags (its 64 gates, K=128, f16) = 64 VGPRs. Bias and the
//     log2e activation prescale are folded here. Output layout is unit-major
//     pairs: dword u = (i_u,f_u), dword 64+u = (g_u,o_u) per row.
//   Phase 2 (rec2): 2 waves x 64. Thread=unit u; wave0 owns (i,f), wave1 (g,o)
//     -> 64 weight dwords/thread (fits the allocator's ~128-VGPR comfort zone;
//     R4's 128 dwords spilled at VGPR_Count=132). 1 coalesced xp dword per
//     thread per step (prefetch depth 4). Acts are bare exp2+rcp (prescaled).
//     2 lgkm-only barriers/step.

#define NI 128
#define NH 64
#define NG 256
#define NB 256
#define NT 1024
#define NC 10

#define LOG2E   1.44269504f
#define TWOLOG2E 2.88539008f

typedef __fp16 half2v __attribute__((ext_vector_type(2)));
typedef __fp16 f16x8  __attribute__((ext_vector_type(8)));
typedef float  f32x4  __attribute__((ext_vector_type(4)));

__device__ __forceinline__ void block_sync_lds() {
    asm volatile("s_waitcnt lgkmcnt(0)\n\ts_barrier" ::: "memory");
}

__device__ __forceinline__ float fast_exp2(float x) {
#if __has_builtin(__builtin_amdgcn_exp2f)
    return __builtin_amdgcn_exp2f(x);
#else
    return __exp2f(x);
#endif
}
__device__ __forceinline__ float fast_rcp(float x) {
    return __builtin_amdgcn_rcpf(x);
}
// sigmoid of prescaled arg: sig2(y) = 1/(1+2^-y) where y = log2e * pre
__device__ __forceinline__ float sig2(float y) {
    y = fminf(fmaxf(y, -30.f), 30.f);
    return fast_rcp(1.f + fast_exp2(-y));
}
// tanh of prescaled arg: y = 2*log2e*pre ; tanh = (2^y - 1)/(2^y + 1)
__device__ __forceinline__ float tanh2(float y) {
    y = fminf(fmaxf(y, -30.f), 30.f);
    float e = fast_exp2(y);
    return (e - 1.f) * fast_rcp(e + 1.f);
}
__device__ __forceinline__ unsigned pack2(float a, float b) {
    half2v h = __builtin_amdgcn_cvt_pkrtz(a, b);
    return __builtin_bit_cast(unsigned, h);
}
__device__ __forceinline__ float dot2(unsigned w, unsigned z, float acc) {
    return __builtin_amdgcn_fdot2(__builtin_bit_cast(half2v, w),
                                  __builtin_bit_cast(half2v, z), acc, false);
}
__device__ __forceinline__ f16x8 pack8(float4 a, float4 b, float s) {
    half2v p0 = __builtin_amdgcn_cvt_pkrtz(a.x * s, a.y * s);
    half2v p1 = __builtin_amdgcn_cvt_pkrtz(a.z * s, a.w * s);
    half2v p2 = __builtin_amdgcn_cvt_pkrtz(b.x * s, b.y * s);
    half2v p3 = __builtin_amdgcn_cvt_pkrtz(b.z * s, b.w * s);
    f16x8 r;
    r[0]=p0[0]; r[1]=p0[1]; r[2]=p1[0]; r[3]=p1[1];
    r[4]=p2[0]; r[5]=p2[1]; r[6]=p3[0]; r[7]=p3[1];
    return r;
}

// ---------------------------------------------------------------- phase 1 ----
// 4096 blocks x 256. Block covers 64 rows (row = b*T + t). Wave w owns ntiles
// {w, w+4, w+8, w+12} -> gates 64*i + 16*w + col (i=0..3), so pack2 across
// i-pairs gives the unit-major (i,f)/(g,o) dwords phase 2 wants.
__global__ __launch_bounds__(256)
void lstm_xproj2(const float* __restrict__ x,
                 const float* __restrict__ W_ih,
                 const float* __restrict__ b_ih,
                 const float* __restrict__ b_hh,
                 unsigned* __restrict__ xp) {
    const int tid  = threadIdx.x;
    const int w    = tid >> 6;
    const int lane = tid & 63;
    const int col  = lane & 15;
    const int quad = lane >> 4;
    const int base = blockIdx.x * 64;

    // ---- B-frags: 4 ntiles x 4 ksteps, f16, prescaled by gate scale ----
    f16x8 bfr[4][4];
    float bias[4];
    #pragma unroll
    for (int i = 0; i < 4; ++i) {
        const int G = 64 * i + 16 * w + col;
        const float s = (i == 2) ? TWOLOG2E : LOG2E;   // g-gate gets 2*log2e
        const float* Wr = W_ih + (size_t)G * NI;
        #pragma unroll
        for (int ks = 0; ks < 4; ++ks) {
            float4 a = *(const float4*)(Wr + 32 * ks + 8 * quad);
            float4 b = *(const float4*)(Wr + 32 * ks + 8 * quad + 4);
            bfr[i][ks] = pack8(a, b, s);
        }
        bias[i] = (b_ih[G] + b_hh[G]) * s;
    }

    f32x4 acc[4][4];
    #pragma unroll
    for (int mt = 0; mt < 4; ++mt)
        #pragma unroll
        for (int i = 0; i < 4; ++i) acc[mt][i] = (f32x4){0.f, 0.f, 0.f, 0.f};

    #pragma unroll
    for (int mt = 0; mt < 4; ++mt) {
        const float* xr = x + (size_t)(base + 16 * mt + col) * NI + 8 * quad;
        f16x8 afr[4];
        #pragma unroll
        for (int ks = 0; ks < 4; ++ks) {
            float4 a = *(const float4*)(xr + 32 * ks);
            float4 b = *(const float4*)(xr + 32 * ks + 4);
            afr[ks] = pack8(a, b, 1.f);
        }
        #pragma unroll
        for (int ks = 0; ks < 4; ++ks)
            #pragma unroll
            for (int i = 0; i < 4; ++i)
                acc[mt][i] = __builtin_amdgcn_mfma_f32_16x16x32_f16(
                    afr[ks], bfr[i][ks], acc[mt][i], 0, 0, 0);
    }

    // epilogue: dword u=(16w+col) packs (i,f); dword 64+u packs (g,o)
    #pragma unroll
    for (int mt = 0; mt < 4; ++mt) {
        #pragma unroll
        for (int r = 0; r < 4; ++r) {
            const size_t row = base + 16 * mt + 4 * quad + r;
            unsigned v0 = pack2(acc[mt][0][r] + bias[0], acc[mt][1][r] + bias[1]);
            unsigned v1 = pack2(acc[mt][2][r] + bias[2], acc[mt][3][r] + bias[3]);
            xp[row * 128 + 16 * w + col]      = v0;
            xp[row * 128 + 64 + 16 * w + col] = v1;
        }
    }
}

// ---------------------------------------------------------------- phase 2 ----
// 256 blocks x 128 threads (2 waves). Thread = unit u. Wave0: gates (i,f);
// wave1: (g,o). 64 packed weight dwords per thread. Biases/prescale already
// folded into xp by phase 1.
__global__ __launch_bounds__(128, 1)
void lstm_rec2(const unsigned* __restrict__ xp,
               const float* __restrict__ W_hh,
               const float* __restrict__ W_cls,
               const float* __restrict__ b_cls,
               float* __restrict__ out) {
    const int b   = blockIdx.x;
    const int tid = threadIdx.x;
    const int wv  = tid >> 6;
    const int u   = tid & 63;

    __shared__ __align__(16) unsigned hz[NH / 2];   // packed h
    __shared__ unsigned go[NH];                      // packed (g,o) per unit
    __shared__ float hf[NH];

    // weight rows: wave0 -> (u, 64+u) = (i,f); wave1 -> (128+u, 192+u) = (g,o)
    const int rA = wv * 128 + u;
    const int rB = rA + 64;
    const float sA = (wv == 0) ? LOG2E : TWOLOG2E;   // g-row prescaled 2*log2e
    const float sB = LOG2E;

    uint4 wa[8], wb[8];
    {
        const float4* pA = (const float4*)(W_hh + (size_t)rA * NH);
        const float4* pB = (const float4*)(W_hh + (size_t)rB * NH);
        #pragma unroll
        for (int k = 0; k < 8; ++k) {
            float4 a = pA[2 * k], b2 = pA[2 * k + 1];
            wa[k] = make_uint4(pack2(a.x * sA, a.y * sA), pack2(a.z * sA, a.w * sA),
                               pack2(b2.x * sA, b2.y * sA), pack2(b2.z * sA, b2.w * sA));
            a = pB[2 * k]; b2 = pB[2 * k + 1];
            wb[k] = make_uint4(pack2(a.x * sB, a.y * sB), pack2(a.z * sB, a.w * sB),
                               pack2(b2.x * sB, b2.y * sB), pack2(b2.z * sB, b2.w * sB));
        }
    }

    if (tid < NH / 2) hz[tid] = 0u;
    block_sync_lds();

    const unsigned* xpb = xp + (size_t)b * NT * 128;
    const int dA = wv * 64 + u;   // wave0: (i,f) dword u; wave1: (g,o) dword 64+u
    unsigned pf[4];
    #pragma unroll
    for (int s = 0; s < 4; ++s) pf[s] = xpb[(size_t)s * 128 + dA];

    float c = 0.f, h = 0.f;
    const uint4* hz4 = (const uint4*)hz;

    for (int tb = 0; tb < NT; tb += 4) {
        #pragma unroll
        for (int s = 0; s < 4; ++s) {
            const unsigned cur = pf[s];
            if (tb + 4 + s < NT) pf[s] = xpb[(size_t)(tb + 4 + s) * 128 + dA];

            float aA0 = 0.f, aA1 = 0.f, aB0 = 0.f, aB1 = 0.f;
            #pragma unroll
            for (int k = 0; k < 8; ++k) {
                uint4 hh = hz4[k];
                aA0 = dot2(wa[k].x, hh.x, aA0); aA0 = dot2(wa[k].y, hh.y, aA0);
                aA1 = dot2(wa[k].z, hh.z, aA1); aA1 = dot2(wa[k].w, hh.w, aA1);
                aB0 = dot2(wb[k].x, hh.x, aB0); aB0 = dot2(wb[k].y, hh.y, aB0);
                aB1 = dot2(wb[k].z, hh.z, aB1); aB1 = dot2(wb[k].w, hh.w, aB1);
            }
            half2v xv = __builtin_bit_cast(half2v, cur);
            float preA = (float)xv[0] + aA0 + aA1;
            float preB = (float)xv[1] + aB0 + aB1;

            if (wv == 1) {                   // g (tanh) and o (sigmoid)
                float gv = tanh2(preA);
                float ov = sig2(preB);
                go[u] = pack2(gv, ov);
            }
            float iv = 0.f, fv = 0.f;
            if (wv == 0) { iv = sig2(preA); fv = sig2(preB); }

            block_sync_lds();                // go visible; hz reads complete

            if (wv == 0) {
                half2v gp = __builtin_bit_cast(half2v, go[u]);
                c = fmaf(fv, c, iv * (float)gp[0]);
                float th = tanh2(TWOLOG2E * c);
                h = (float)gp[1] * th;
                float hn = __shfl_down(h, 1);
                if ((u & 1) == 0) hz[u >> 1] = pack2(h, hn);
            }
            block_sync_lds();                // new hz visible
        }
    }

    if (wv == 0) hf[u] = h;
    block_sync_lds();
    if (tid < NC) {
        float acc = b_cls[tid];
        const float* wc = W_cls + tid * NH;
        #pragma unroll 8
        for (int k = 0; k < NH; ++k) acc = fmaf(wc[k], hf[k], acc);
        out[b * NC + tid] = acc;
    }
}

// ------------------------------------------------------------- fallback (R3) --
__device__ __forceinline__ float fast_sigmoid(float x) {
    x = fminf(fmaxf(x, -30.f), 30.f);
    return 1.f / (1.f + __expf(-x));
}
__device__ __forceinline__ float fast_tanh(float x) {
    x = fminf(fmaxf(x, -15.f), 15.f);
    float e = __expf(2.f * x);
    return (e - 1.f) / (e + 1.f);
}

__global__ __launch_bounds__(NG, 1)
void lstm_fused_f16_kernel(const float* __restrict__ x,
                           const float* __restrict__ W_ih,
                           const float* __restrict__ W_hh,
                           const float* __restrict__ b_ih,
                           const float* __restrict__ b_hh,
                           const float* __restrict__ W_cls,
                           const float* __restrict__ b_cls,
                           float* __restrict__ out) {
    const int b = blockIdx.x;
    const int g = threadIdx.x;
    __shared__ __align__(16) unsigned zs[NI / 2 + NH / 2];
    __shared__ float acts[NG];
    unsigned wp[96];
    {
        const float2* p = (const float2*)(W_ih + (size_t)g * NI);
        #pragma unroll
        for (int jj = 0; jj < NI / 2; ++jj) { float2 v = p[jj]; wp[jj] = pack2(v.x, v.y); }
        const float2* q = (const float2*)(W_hh + (size_t)g * NH);
        #pragma unroll
        for (int jj = 0; jj < NH / 2; ++jj) { float2 v = q[jj]; wp[NI / 2 + jj] = pack2(v.x, v.y); }
    }
    const float bias = b_ih[g] + b_hh[g];
    const float* xrow = x + (size_t)b * NT * NI;
    const int lane1 = g - 64;
    float2 xpre = make_float2(0.f, 0.f);
    if (g >= 64 && g < 128) {
        float2 v = ((const float2*)xrow)[lane1];
        zs[lane1] = pack2(v.x, v.y);
        xpre = ((const float2*)(xrow + NI))[lane1];
    }
    if (g < NH / 2) zs[NI / 2 + g] = 0u;
    float c = 0.f;
    const uint4* zs4 = (const uint4*)zs;
    for (int t = 0; t < NT; ++t) {
        block_sync_lds();
        float a0 = bias, a1 = 0.f, a2 = 0.f, a3 = 0.f;
        #pragma unroll
        for (int k = 0; k < 24; ++k) {
            uint4 zv = zs4[k];
            a0 = dot2(wp[4 * k + 0], zv.x, a0);
            a1 = dot2(wp[4 * k + 1], zv.y, a1);
            a2 = dot2(wp[4 * k + 2], zv.z, a2);
            a3 = dot2(wp[4 * k + 3], zv.w, a3);
        }
        float pre = (a0 + a1) + (a2 + a3);
        float av = (g >= 2 * NH && g < 3 * NH) ? fast_tanh(pre) : fast_sigmoid(pre);
        acts[g] = av;
        block_sync_lds();
        if (g < NH) {
            float i_t = acts[g];
            float f_t = acts[NH + g];
            float g_t = acts[2 * NH + g];
            float o_t = acts[3 * NH + g];
            c = fmaf(f_t, c, i_t * g_t);
            float hv = o_t * fast_tanh(c);
            float hn = __shfl_down(hv, 1);
            if ((g & 1) == 0) zs[NI / 2 + (g >> 1)] = pack2(hv, hn);
        } else if (g < 128) {
            if (t + 1 < NT) zs[lane1] = pack2(xpre.x, xpre.y);
            if (t + 2 < NT) xpre = ((const float2*)(xrow + (size_t)(t + 2) * NI))[lane1];
        }
    }
    block_sync_lds();
    if (g < NC) {
        float acc = b_cls[g];
        const float* wc = W_cls + g * NH;
        #pragma unroll
        for (int jj = 0; jj < NH / 2; ++jj) {
            half2v hp = __builtin_bit_cast(half2v, zs[NI / 2 + jj]);
            acc = fmaf(wc[2 * jj],     (float)hp[0], acc);
            acc = fmaf(wc[2 * jj + 1], (float)hp[1], acc);
        }
        out[b * NC + g] = acc;
    }
}

extern "C" void kernel_launch(void* const* d_in, const int* in_sizes, int n_in,
                              void* d_out, int out_size, void* d_ws, size_t ws_size,
                              hipStream_t stream) {
    const float* x     = (const float*)d_in[0];
    const float* W_ih  = (const float*)d_in[1];
    const float* W_hh  = (const float*)d_in[2];
    const float* b_ih  = (const float*)d_in[3];
    const float* b_hh  = (const float*)d_in[4];
    const float* W_cls = (const float*)d_in[5];
    const float* b_cls = (const float*)d_in[6];
    float* out = (float*)d_out;

    const size_t need = (size_t)NB * NT * 128 * sizeof(unsigned);   // 134 MB
    if (ws_size >= need) {
        unsigned* xp = (unsigned*)d_ws;
        lstm_xproj2<<<(NB * NT) / 64, 256, 0, stream>>>(x, W_ih, b_ih, b_hh, xp);
        lstm_rec2<<<NB, 128, 0, stream>>>(xp, W_hh, W_cls, b_cls, out);
    } else {
        lstm_fused_f16_kernel<<<NB, NG, 0, stream>>>(x, W_ih, W_hh, b_ih, b_hh,
                                                     W_cls, b_cls, out);
    }
}

// Round 6
// 745.409 us; speedup vs baseline: 1.2843x; 1.2843x over previous
//
#include <hip/hip_runtime.h>

// TinyLSTM: I=128, H=64, C=10, B=256, T=1024
// Round 6: MFMA recurrence.
//   Phase 1 (xproj3): x@W_ih^T, M=262144 N=256 K=128. A staged in LDS (16 KB,
//     XOR-swizzled, coalesced global loads), B (W_ih) in 64 VGPRs of frags.
//     Output xp[row][128 dwords], dword d = packf16(gate d, gate d+128),
//     bias + log2e prescale folded (g-gates 2*log2e).
//   Phase 2 (rec3): 16 blocks x 256 thr; block owns 16 batch chains (MFMA N).
//     gates(256x16) = (s*W_hh)(256x64) @ H(64x16) per step via 8 MFMA/wave.
//     Wave w owns mtiles {w,w+4,w+8,w+12} -> lane holds i,f,g,o of units
//     16w+quad*4+{0..3} for batch col -> lane-local c/h update. W_hh A-frags
//     = 32 VGPRs/lane (allocator-friendly; R3/R4/R5 all proved >=64 private
//     dwords/thread get demoted). H double-buffered in LDS -> 1 barrier/step.

#define NI 128
#define NH 64
#define NG 256
#define NB 256
#define NT 1024
#define NC 10

#define LOG2E    1.44269504f
#define TWOLOG2E 2.88539008f

typedef __fp16 half2v __attribute__((ext_vector_type(2)));
typedef __fp16 f16x8  __attribute__((ext_vector_type(8)));
typedef float  f32x4  __attribute__((ext_vector_type(4)));

__device__ __forceinline__ void block_sync_lds() {
    asm volatile("s_waitcnt lgkmcnt(0)\n\ts_barrier" ::: "memory");
}
__device__ __forceinline__ float fast_exp2(float x) {
#if __has_builtin(__builtin_amdgcn_exp2f)
    return __builtin_amdgcn_exp2f(x);
#else
    return __exp2f(x);
#endif
}
__device__ __forceinline__ float fast_rcp(float x) {
    return __builtin_amdgcn_rcpf(x);
}
// sigmoid with prescaled arg y = log2e*pre: 1/(1+2^-y). No clamp needed:
// y->-inf: exp2(+inf)=inf, rcp(inf)=0 OK; y->+inf: exp2(-inf)=0 -> 1 OK.
__device__ __forceinline__ float sig2(float y) {
    return fast_rcp(1.f + fast_exp2(-y));
}
// tanh with prescaled arg y = 2*log2e*pre. Clamp top to avoid inf*0=NaN.
__device__ __forceinline__ float tanh2(float y) {
    float e = fast_exp2(fminf(y, 60.f));
    return (e - 1.f) * fast_rcp(e + 1.f);
}
__device__ __forceinline__ unsigned pack2(float a, float b) {
    half2v h = __builtin_amdgcn_cvt_pkrtz(a, b);
    return __builtin_bit_cast(unsigned, h);
}
__device__ __forceinline__ float dot2(unsigned w, unsigned z, float acc) {
    return __builtin_amdgcn_fdot2(__builtin_bit_cast(half2v, w),
                                  __builtin_bit_cast(half2v, z), acc, false);
}
__device__ __forceinline__ f16x8 pack8(float4 a, float4 b, float s) {
    half2v p0 = __builtin_amdgcn_cvt_pkrtz(a.x * s, a.y * s);
    half2v p1 = __builtin_amdgcn_cvt_pkrtz(a.z * s, a.w * s);
    half2v p2 = __builtin_amdgcn_cvt_pkrtz(b.x * s, b.y * s);
    half2v p3 = __builtin_amdgcn_cvt_pkrtz(b.z * s, b.w * s);
    f16x8 r;
    r[0]=p0[0]; r[1]=p0[1]; r[2]=p1[0]; r[3]=p1[1];
    r[4]=p2[0]; r[5]=p2[1]; r[6]=p3[0]; r[7]=p3[1];
    return r;
}

// ---------------------------------------------------------------- phase 1 ----
// 4096 blocks x 256. Block: rows [bid*64, +64), all 256 gates, K=128.
__global__ __launch_bounds__(256)
void lstm_xproj3(const float* __restrict__ x,
                 const float* __restrict__ W_ih,
                 const float* __restrict__ b_ih,
                 const float* __restrict__ b_hh,
                 unsigned* __restrict__ xp) {
    __shared__ __align__(16) unsigned short A[64 * 128];   // 16 KB, swizzled

    const int tid  = threadIdx.x;
    const int w    = tid >> 6;
    const int lane = tid & 63;
    const int col  = lane & 15;
    const int quad = lane >> 4;
    const size_t base = (size_t)blockIdx.x * 64;

    // B-frags (W_ih) in regs: 4 ntiles x 4 ksteps; bias+prescale folded.
    f16x8 bfr[4][4];
    float bias[4];
    #pragma unroll
    for (int i = 0; i < 4; ++i) {
        const int G = 64 * i + 16 * w + col;
        const float s = (i == 2) ? TWOLOG2E : LOG2E;
        const float* Wr = W_ih + (size_t)G * NI;
        #pragma unroll
        for (int ks = 0; ks < 4; ++ks) {
            float4 a4 = *(const float4*)(Wr + 32 * ks + 8 * quad);
            float4 b4 = *(const float4*)(Wr + 32 * ks + 8 * quad + 4);
            bfr[i][ks] = pack8(a4, b4, s);
        }
        bias[i] = (b_ih[G] + b_hh[G]) * s;
    }

    // stage A: coalesced, pack f32->f16, XOR-swizzle 16B chunks by row&7.
    const float4* xb = (const float4*)(x + base * NI);
    #pragma unroll
    for (int j = 0; j < 8; ++j) {
        int idx = j * 256 + tid;       // float4 index in 64x32 tile
        float4 v = xb[idx];
        int row = idx >> 5, q = idx & 31;
        int cs = (q >> 1) ^ (row & 7);
        int hf = q & 1;
        *(uint2*)((char*)A + row * 256 + cs * 16 + hf * 8) =
            make_uint2(pack2(v.x, v.y), pack2(v.z, v.w));
    }
    __syncthreads();

    f32x4 acc[4][4];
    #pragma unroll
    for (int mt = 0; mt < 4; ++mt)
        #pragma unroll
        for (int i = 0; i < 4; ++i) acc[mt][i] = (f32x4){0.f, 0.f, 0.f, 0.f};

    #pragma unroll
    for (int mt = 0; mt < 4; ++mt) {
        const int arow = 16 * mt + col;   // A-frag: m = lane&15
        #pragma unroll
        for (int ks = 0; ks < 4; ++ks) {
            int cs = (ks * 4 + quad) ^ (arow & 7);
            f16x8 afr = *(const f16x8*)((char*)A + arow * 256 + cs * 16);
            #pragma unroll
            for (int i = 0; i < 4; ++i)
                acc[mt][i] = __builtin_amdgcn_mfma_f32_16x16x32_f16(
                    afr, bfr[i][ks], acc[mt][i], 0, 0, 0);
        }
    }

    // epilogue: dword d = pack(gate d, gate d+128); d = 16w+col and 64+16w+col
    #pragma unroll
    for (int mt = 0; mt < 4; ++mt) {
        #pragma unroll
        for (int r = 0; r < 4; ++r) {
            size_t row = base + 16 * mt + 4 * quad + r;
            unsigned v0 = pack2(acc[mt][0][r] + bias[0], acc[mt][2][r] + bias[2]);
            unsigned v1 = pack2(acc[mt][1][r] + bias[1], acc[mt][3][r] + bias[3]);
            xp[row * 128 + 16 * w + col]      = v0;
            xp[row * 128 + 64 + 16 * w + col] = v1;
        }
    }
}

// ---------------------------------------------------------------- phase 2 ----
// 16 blocks x 256 thr. Block = batch group [bb*16, +16).
__global__ __launch_bounds__(256, 1)
void lstm_rec3(const unsigned* __restrict__ xp,
               const float* __restrict__ W_hh,
               const float* __restrict__ W_cls,
               const float* __restrict__ b_cls,
               float* __restrict__ out) {
    const int tid  = threadIdx.x;
    const int w    = tid >> 6;
    const int lane = tid & 63;
    const int col  = lane & 15;     // batch within group (B/C-operand n)
    const int quad = lane >> 4;
    const int bb   = blockIdx.x;

    __shared__ __align__(16) unsigned short H2[2][16][72];   // dbl-buf h (f16)

    // A-frags: prescaled W_hh for mtiles {w, w+4, w+8, w+12} -> 32 VGPRs.
    f16x8 afr[4][2];
    #pragma unroll
    for (int i = 0; i < 4; ++i) {
        const int grow = 16 * (w + 4 * i) + col;   // A-row m = lane&15
        const float s = (i == 2) ? TWOLOG2E : LOG2E;
        const float* Wr = W_hh + (size_t)grow * NH;
        #pragma unroll
        for (int ks = 0; ks < 2; ++ks) {
            float4 a4 = *(const float4*)(Wr + ks * 32 + quad * 8);
            float4 b4 = *(const float4*)(Wr + ks * 32 + quad * 8 + 4);
            afr[i][ks] = pack8(a4, b4, s);
        }
    }

    // zero both H buffers
    for (int i = tid; i < 2 * 16 * 72; i += 256) ((unsigned short*)H2)[i] = 0;

    const int u0 = 16 * w + 4 * quad;      // first of this lane's 4 units
    const unsigned* xpl = xp + ((size_t)(bb * 16 + col) * NT) * 128 + u0;
    const unsigned* xph = xpl + 64;
    uint4 pfl[2], pfh[2];
    pfl[0] = *(const uint4*)(xpl);       pfh[0] = *(const uint4*)(xph);
    pfl[1] = *(const uint4*)(xpl + 128); pfh[1] = *(const uint4*)(xph + 128);

    f32x4 c4 = {0.f, 0.f, 0.f, 0.f};
    float hv[4];

    block_sync_lds();   // H zero-init visible

    auto step = [&](int t, const unsigned short* Hr, unsigned short* Hw,
                    uint4& spl, uint4& sph) {
        // B-frags: H[k=ks*32+quad*8+j][n=col]
        f16x8 hb0 = *(const f16x8*)(Hr + col * 72 + quad * 8);
        f16x8 hb1 = *(const f16x8*)(Hr + col * 72 + 32 + quad * 8);
        f32x4 g0 = {0.f,0.f,0.f,0.f}, g1 = g0, g2 = g0, g3 = g0;
        g0 = __builtin_amdgcn_mfma_f32_16x16x32_f16(afr[0][0], hb0, g0, 0,0,0);
        g1 = __builtin_amdgcn_mfma_f32_16x16x32_f16(afr[1][0], hb0, g1, 0,0,0);
        g2 = __builtin_amdgcn_mfma_f32_16x16x32_f16(afr[2][0], hb0, g2, 0,0,0);
        g3 = __builtin_amdgcn_mfma_f32_16x16x32_f16(afr[3][0], hb0, g3, 0,0,0);
        g0 = __builtin_amdgcn_mfma_f32_16x16x32_f16(afr[0][1], hb1, g0, 0,0,0);
        g1 = __builtin_amdgcn_mfma_f32_16x16x32_f16(afr[1][1], hb1, g1, 0,0,0);
        g2 = __builtin_amdgcn_mfma_f32_16x16x32_f16(afr[2][1], hb1, g2, 0,0,0);
        g3 = __builtin_amdgcn_mfma_f32_16x16x32_f16(afr[3][1], hb1, g3, 0,0,0);

        uint4 xlo = spl, xhi = sph;
        int tn = (t + 2 < NT) ? (t + 2) : (NT - 1);
        spl = *(const uint4*)(xpl + (size_t)tn * 128);
        sph = *(const uint4*)(xph + (size_t)tn * 128);

        unsigned xl[4] = {xlo.x, xlo.y, xlo.z, xlo.w};
        unsigned xh[4] = {xhi.x, xhi.y, xhi.z, xhi.w};
        #pragma unroll
        for (int r = 0; r < 4; ++r) {
            half2v ig = __builtin_bit_cast(half2v, xl[r]);   // (i, g)
            half2v fo = __builtin_bit_cast(half2v, xh[r]);   // (f, o)
            float pre_i = g0[r] + (float)ig[0];
            float pre_f = g1[r] + (float)fo[0];
            float pre_g = g2[r] + (float)ig[1];
            float pre_o = g3[r] + (float)fo[1];
            float iv = sig2(pre_i);
            float fv = sig2(pre_f);
            float gv = tanh2(pre_g);
            float ov = sig2(pre_o);
            c4[r] = fmaf(fv, c4[r], iv * gv);
            hv[r] = ov * tanh2(TWOLOG2E * c4[r]);
        }
        *(uint2*)(Hw + col * 72 + u0) =
            make_uint2(pack2(hv[0], hv[1]), pack2(hv[2], hv[3]));
        block_sync_lds();
    };

    for (int t = 0; t < NT; t += 2) {
        step(t,     &H2[0][0][0], &H2[1][0][0], pfl[0], pfh[0]);
        step(t + 1, &H2[1][0][0], &H2[0][0][0], pfl[1], pfh[1]);
    }
    // final h is in H2[0] (step 1023 writes buf 0); barrier already done.

    if (tid < 16 * NC) {
        int bl = tid / NC, cl = tid % NC;
        float acc = b_cls[cl];
        const float* wc = W_cls + cl * NH;
        const unsigned short* hrow = &H2[0][bl][0];
        #pragma unroll 8
        for (int k = 0; k < NH; ++k)
            acc = fmaf(wc[k], (float)*(const __fp16*)(hrow + k), acc);
        out[(bb * 16 + bl) * NC + cl] = acc;
    }
}

// ------------------------------------------------------------- fallback (R3) --
__device__ __forceinline__ float fast_sigmoid(float x) {
    x = fminf(fmaxf(x, -30.f), 30.f);
    return 1.f / (1.f + __expf(-x));
}
__device__ __forceinline__ float fast_tanh(float x) {
    x = fminf(fmaxf(x, -15.f), 15.f);
    float e = __expf(2.f * x);
    return (e - 1.f) / (e + 1.f);
}

__global__ __launch_bounds__(NG, 1)
void lstm_fused_f16_kernel(const float* __restrict__ x,
                           const float* __restrict__ W_ih,
                           const float* __restrict__ W_hh,
                           const float* __restrict__ b_ih,
                           const float* __restrict__ b_hh,
                           const float* __restrict__ W_cls,
                           const float* __restrict__ b_cls,
                           float* __restrict__ out) {
    const int b = blockIdx.x;
    const int g = threadIdx.x;
    __shared__ __align__(16) unsigned zs[NI / 2 + NH / 2];
    __shared__ float acts[NG];
    unsigned wp[96];
    {
        const float2* p = (const float2*)(W_ih + (size_t)g * NI);
        #pragma unroll
        for (int jj = 0; jj < NI / 2; ++jj) { float2 v = p[jj]; wp[jj] = pack2(v.x, v.y); }
        const float2* q = (const float2*)(W_hh + (size_t)g * NH);
        #pragma unroll
        for (int jj = 0; jj < NH / 2; ++jj) { float2 v = q[jj]; wp[NI / 2 + jj] = pack2(v.x, v.y); }
    }
    const float bias = b_ih[g] + b_hh[g];
    const float* xrow = x + (size_t)b * NT * NI;
    const int lane1 = g - 64;
    float2 xpre = make_float2(0.f, 0.f);
    if (g >= 64 && g < 128) {
        float2 v = ((const float2*)xrow)[lane1];
        zs[lane1] = pack2(v.x, v.y);
        xpre = ((const float2*)(xrow + NI))[lane1];
    }
    if (g < NH / 2) zs[NI / 2 + g] = 0u;
    float c = 0.f;
    const uint4* zs4 = (const uint4*)zs;
    for (int t = 0; t < NT; ++t) {
        block_sync_lds();
        float a0 = bias, a1 = 0.f, a2 = 0.f, a3 = 0.f;
        #pragma unroll
        for (int k = 0; k < 24; ++k) {
            uint4 zv = zs4[k];
            a0 = dot2(wp[4 * k + 0], zv.x, a0);
            a1 = dot2(wp[4 * k + 1], zv.y, a1);
            a2 = dot2(wp[4 * k + 2], zv.z, a2);
            a3 = dot2(wp[4 * k + 3], zv.w, a3);
        }
        float pre = (a0 + a1) + (a2 + a3);
        float av = (g >= 2 * NH && g < 3 * NH) ? fast_tanh(pre) : fast_sigmoid(pre);
        acts[g] = av;
        block_sync_lds();
        if (g < NH) {
            float i_t = acts[g];
            float f_t = acts[NH + g];
            float g_t = acts[2 * NH + g];
            float o_t = acts[3 * NH + g];
            c = fmaf(f_t, c, i_t * g_t);
            float hv = o_t * fast_tanh(c);
            float hn = __shfl_down(hv, 1);
            if ((g & 1) == 0) zs[NI / 2 + (g >> 1)] = pack2(hv, hn);
        } else if (g < 128) {
            if (t + 1 < NT) zs[lane1] = pack2(xpre.x, xpre.y);
            if (t + 2 < NT) xpre = ((const float2*)(xrow + (size_t)(t + 2) * NI))[lane1];
        }
    }
    block_sync_lds();
    if (g < NC) {
        float acc = b_cls[g];
        const float* wc = W_cls + g * NH;
        #pragma unroll
        for (int jj = 0; jj < NH / 2; ++jj) {
            half2v hp = __builtin_bit_cast(half2v, zs[NI / 2 + jj]);
            acc = fmaf(wc[2 * jj],     (float)hp[0], acc);
            acc = fmaf(wc[2 * jj + 1], (float)hp[1], acc);
        }
        out[b * NC + g] = acc;
    }
}

extern "C" void kernel_launch(void* const* d_in, const int* in_sizes, int n_in,
                              void* d_out, int out_size, void* d_ws, size_t ws_size,
                              hipStream_t stream) {
    const float* x     = (const float*)d_in[0];
    const float* W_ih  = (const float*)d_in[1];
    const float* W_hh  = (const float*)d_in[2];
    const float* b_ih  = (const float*)d_in[3];
    const float* b_hh  = (const float*)d_in[4];
    const float* W_cls = (const float*)d_in[5];
    const float* b_cls = (const float*)d_in[6];
    float* out = (float*)d_out;

    const size_t need = (size_t)NB * NT * 128 * sizeof(unsigned);   // 134 MB
    if (ws_size >= need) {
        unsigned* xp = (unsigned*)d_ws;
        lstm_xproj3<<<(NB * NT) / 64, 256, 0, stream>>>(x, W_ih, b_ih, b_hh, xp);
        lstm_rec3<<<NB / 16, 256, 0, stream>>>(xp, W_hh, W_cls, b_cls, out);
    } else {
        lstm_fused_f16_kernel<<<NB, NG, 0, stream>>>(x, W_ih, W_hh, b_ih, b_hh,
                                                     W_cls, b_cls, out);
    }
}

// Round 7
// 612.627 us; speedup vs baseline: 1.5627x; 1.2167x over previous
//
#include <hip/hip_runtime.h>

// TinyLSTM: I=128, H=64, C=10, B=256, T=1024
// Round 7: SINGLE fused MFMA kernel. 64 blocks x 256 thr; block owns 4 batch
// chains. Per step, gates(256x16cols) = [s*W_ih | s*W_hh](256x192) @
// [x_t; h_{t-1}](192x16) via 24 MFMA/wave (K=192), batch in MFMA N (4 real
// cols, replicated x4 -> broadcast LDS reads, free). Lane (col,quad) of wave
// w activates exactly ONE unit: u = 16w+4quad+(col>>2), batch = col&3 --
// bijective, so trans work = 10/lane/step (R6 had 40 via replication).
// Weights live as MFMA A-frags (afrX 64 + afrH 32 VGPRs -- R6's VGPR_Count=56
// proved frag operands stay resident, unlike per-thread arrays R3-R5).
// LDS strides padded to 144/80 halves: all reads/writes <=2-way (R6's 72-half
// stride cost 786k conflicts). One lgkm-only barrier/step. No workspace.

#define NI 128
#define NH 64
#define NG 256
#define NB 256
#define NT 1024
#define NC 10

#define LOG2E    1.44269504f
#define TWOLOG2E 2.88539008f

typedef __fp16 half2v __attribute__((ext_vector_type(2)));
typedef __fp16 f16x8  __attribute__((ext_vector_type(8)));
typedef float  f32x4  __attribute__((ext_vector_type(4)));

__device__ __forceinline__ void block_sync_lds() {
    asm volatile("s_waitcnt lgkmcnt(0)\n\ts_barrier" ::: "memory");
}
__device__ __forceinline__ float fast_exp2(float x) {
#if __has_builtin(__builtin_amdgcn_exp2f)
    return __builtin_amdgcn_exp2f(x);
#else
    return __exp2f(x);
#endif
}
__device__ __forceinline__ float fast_rcp(float x) {
    return __builtin_amdgcn_rcpf(x);
}
// sigmoid, prescaled arg y = log2e*pre. y->-inf: rcp(inf)=0; y->+inf: 1.
__device__ __forceinline__ float sig2(float y) {
    return fast_rcp(1.f + fast_exp2(-y));
}
// tanh, prescaled arg y = 2*log2e*pre; clamp top to avoid inf/inf.
__device__ __forceinline__ float tanh2(float y) {
    float e = fast_exp2(fminf(y, 60.f));
    return (e - 1.f) * fast_rcp(e + 1.f);
}
__device__ __forceinline__ unsigned pack2(float a, float b) {
    half2v h = __builtin_amdgcn_cvt_pkrtz(a, b);
    return __builtin_bit_cast(unsigned, h);
}
__device__ __forceinline__ f16x8 pack8(float4 a, float4 b, float s) {
    half2v p0 = __builtin_amdgcn_cvt_pkrtz(a.x * s, a.y * s);
    half2v p1 = __builtin_amdgcn_cvt_pkrtz(a.z * s, a.w * s);
    half2v p2 = __builtin_amdgcn_cvt_pkrtz(b.x * s, b.y * s);
    half2v p3 = __builtin_amdgcn_cvt_pkrtz(b.z * s, b.w * s);
    f16x8 r;
    r[0]=p0[0]; r[1]=p0[1]; r[2]=p1[0]; r[3]=p1[1];
    r[4]=p2[0]; r[5]=p2[1]; r[6]=p3[0]; r[7]=p3[1];
    return r;
}

#define XP 144   // X row stride (halves): 288 B, 16B-aligned, max 2-way banks
#define HP 80    // H row stride (halves): 160 B, 16B-aligned, max 2-way banks

__global__ __launch_bounds__(256, 1)
void lstm_one(const float* __restrict__ x,
              const float* __restrict__ W_ih,
              const float* __restrict__ W_hh,
              const float* __restrict__ b_ih,
              const float* __restrict__ b_hh,
              const float* __restrict__ W_cls,
              const float* __restrict__ b_cls,
              float* __restrict__ out) {
    const int tid  = threadIdx.x;
    const int w    = tid >> 6;     // wave: owns units [16w, 16w+16)
    const int lane = tid & 63;
    const int col  = lane & 15;    // MFMA n-column
    const int quad = lane >> 4;
    const int bb   = blockIdx.x;   // batches [4bb, 4bb+4)
    const int bcol = col & 3;      // batch within group (cols replicate x4)
    const int cr   = col >> 2;     // the one C-row r this lane activates

    __shared__ __align__(16) __fp16 X2[2][4][XP];  // x_t packed f16, dbl-buf
    __shared__ __align__(16) __fp16 H2[2][4][HP];  // h packed f16, dbl-buf

    // ---- A-frags: A[m=lane&15][k=quad*8+j]; row = gate 64i+16w+col ----
    f16x8 afrX[4][4];   // W_ih, K=128 (4 ksteps)   -> 64 VGPRs
    f16x8 afrH[4][2];   // W_hh, K=64  (2 ksteps)   -> 32 VGPRs
    f32x4 biasf[4];     // bias in C layout: [i][r] for unit 16w+4quad+r
    #pragma unroll
    for (int i = 0; i < 4; ++i) {
        const int grow = 64 * i + 16 * w + col;
        const float s = (i == 2) ? TWOLOG2E : LOG2E;
        const float* Wx = W_ih + (size_t)grow * NI;
        #pragma unroll
        for (int ks = 0; ks < 4; ++ks) {
            float4 a4 = *(const float4*)(Wx + ks * 32 + quad * 8);
            float4 b4 = *(const float4*)(Wx + ks * 32 + quad * 8 + 4);
            afrX[i][ks] = pack8(a4, b4, s);
        }
        const float* Wh = W_hh + (size_t)grow * NH;
        #pragma unroll
        for (int ks = 0; ks < 2; ++ks) {
            float4 a4 = *(const float4*)(Wh + ks * 32 + quad * 8);
            float4 b4 = *(const float4*)(Wh + ks * 32 + quad * 8 + 4);
            afrH[i][ks] = pack8(a4, b4, s);
        }
        #pragma unroll
        for (int r = 0; r < 4; ++r) {
            const int u = 64 * i + 16 * w + 4 * quad + r;
            biasf[i][r] = (b_ih[u] + b_hh[u]) * s;
        }
    }

    // ---- prologue: stage x[0], prefetch x[1], zero h ----
    const float* xlane = x + ((size_t)(4 * bb + w) * NT) * NI + 2 * lane;
    {
        float2 v0 = *(const float2*)(xlane);
        *(unsigned*)(&X2[0][w][2 * lane]) = pack2(v0.x, v0.y);
    }
    float2 xreg = *(const float2*)(xlane + NI);
    if (tid < 2 * 4 * HP / 2) ((unsigned*)H2)[tid] = 0u;   // zero both H bufs
    __syncthreads();

    float c = 0.f;

    auto step = [&](int t, int cur) {
        // B-frags: B[k=ks*32+quad*8+j][n=col] from row bcol (broadcast x4)
        const __fp16* Xc = &X2[cur][bcol][quad * 8];
        f16x8 xb0 = *(const f16x8*)(Xc);
        f16x8 xb1 = *(const f16x8*)(Xc + 32);
        f16x8 xb2 = *(const f16x8*)(Xc + 64);
        f16x8 xb3 = *(const f16x8*)(Xc + 96);
        const __fp16* Hc = &H2[cur][bcol][quad * 8];
        f16x8 hb0 = *(const f16x8*)(Hc);
        f16x8 hb1 = *(const f16x8*)(Hc + 32);

        // stage x[t+1] into other buffer; prefetch x[t+2] (off critical path)
        *(unsigned*)(&X2[cur ^ 1][w][2 * lane]) = pack2(xreg.x, xreg.y);
        const int tn = (t + 2 < NT) ? (t + 2) : (NT - 1);
        xreg = *(const float2*)(xlane + (size_t)tn * NI);

        // 24 MFMA: 4 gate-blocks x (4 x-ksteps + 2 h-ksteps), bias-seeded
        f32x4 a0 = biasf[0], a1 = biasf[1], a2 = biasf[2], a3 = biasf[3];
        a0 = __builtin_amdgcn_mfma_f32_16x16x32_f16(afrX[0][0], xb0, a0, 0,0,0);
        a1 = __builtin_amdgcn_mfma_f32_16x16x32_f16(afrX[1][0], xb0, a1, 0,0,0);
        a2 = __builtin_amdgcn_mfma_f32_16x16x32_f16(afrX[2][0], xb0, a2, 0,0,0);
        a3 = __builtin_amdgcn_mfma_f32_16x16x32_f16(afrX[3][0], xb0, a3, 0,0,0);
        a0 = __builtin_amdgcn_mfma_f32_16x16x32_f16(afrX[0][1], xb1, a0, 0,0,0);
        a1 = __builtin_amdgcn_mfma_f32_16x16x32_f16(afrX[1][1], xb1, a1, 0,0,0);
        a2 = __builtin_amdgcn_mfma_f32_16x16x32_f16(afrX[2][1], xb1, a2, 0,0,0);
        a3 = __builtin_amdgcn_mfma_f32_16x16x32_f16(afrX[3][1], xb1, a3, 0,0,0);
        a0 = __builtin_amdgcn_mfma_f32_16x16x32_f16(afrX[0][2], xb2, a0, 0,0,0);
        a1 = __builtin_amdgcn_mfma_f32_16x16x32_f16(afrX[1][2], xb2, a1, 0,0,0);
        a2 = __builtin_amdgcn_mfma_f32_16x16x32_f16(afrX[2][2], xb2, a2, 0,0,0);
        a3 = __builtin_amdgcn_mfma_f32_16x16x32_f16(afrX[3][2], xb2, a3, 0,0,0);
        a0 = __builtin_amdgcn_mfma_f32_16x16x32_f16(afrX[0][3], xb3, a0, 0,0,0);
        a1 = __builtin_amdgcn_mfma_f32_16x16x32_f16(afrX[1][3], xb3, a1, 0,0,0);
        a2 = __builtin_amdgcn_mfma_f32_16x16x32_f16(afrX[2][3], xb3, a2, 0,0,0);
        a3 = __builtin_amdgcn_mfma_f32_16x16x32_f16(afrX[3][3], xb3, a3, 0,0,0);
        a0 = __builtin_amdgcn_mfma_f32_16x16x32_f16(afrH[0][0], hb0, a0, 0,0,0);
        a1 = __builtin_amdgcn_mfma_f32_16x16x32_f16(afrH[1][0], hb0, a1, 0,0,0);
        a2 = __builtin_amdgcn_mfma_f32_16x16x32_f16(afrH[2][0], hb0, a2, 0,0,0);
        a3 = __builtin_amdgcn_mfma_f32_16x16x32_f16(afrH[3][0], hb0, a3, 0,0,0);
        a0 = __builtin_amdgcn_mfma_f32_16x16x32_f16(afrH[0][1], hb1, a0, 0,0,0);
        a1 = __builtin_amdgcn_mfma_f32_16x16x32_f16(afrH[1][1], hb1, a1, 0,0,0);
        a2 = __builtin_amdgcn_mfma_f32_16x16x32_f16(afrH[2][1], hb1, a2, 0,0,0);
        a3 = __builtin_amdgcn_mfma_f32_16x16x32_f16(afrH[3][1], hb1, a3, 0,0,0);

        // activation: this lane's ONE unit (u = 16w+4quad+cr, batch bcol)
        float iv = sig2(a0[cr]);
        float fv = sig2(a1[cr]);
        float gv = tanh2(a2[cr]);
        float ov = sig2(a3[cr]);
        c = fmaf(fv, c, iv * gv);
        float h = ov * tanh2(TWOLOG2E * c);

        H2[cur ^ 1][bcol][16 * w + 4 * quad + cr] = (__fp16)h;
        block_sync_lds();
    };

    for (int t = 0; t < NT; t += 2) {
        step(t, 0);
        step(t + 1, 1);
    }
    // final h is in H2[0] (step 1023 writes buf (1023+1)&1 = 0); barrier done.

    if (tid < 4 * NC) {
        const int bl = tid / NC, cl = tid % NC;
        float acc = b_cls[cl];
        const float* wc = W_cls + cl * NH;
        #pragma unroll 8
        for (int k = 0; k < NH; ++k)
            acc = fmaf(wc[k], (float)H2[0][bl][k], acc);
        out[(4 * bb + bl) * NC + cl] = acc;
    }
}

extern "C" void kernel_launch(void* const* d_in, const int* in_sizes, int n_in,
                              void* d_out, int out_size, void* d_ws, size_t ws_size,
                              hipStream_t stream) {
    const float* x     = (const float*)d_in[0];
    const float* W_ih  = (const float*)d_in[1];
    const float* W_hh  = (const float*)d_in[2];
    const float* b_ih  = (const float*)d_in[3];
    const float* b_hh  = (const float*)d_in[4];
    const float* W_cls = (const float*)d_in[5];
    const float* b_cls = (const float*)d_in[6];
    float* out = (float*)d_out;

    lstm_one<<<NB / 4, 256, 0, stream>>>(x, W_ih, W_hh, b_ih, b_hh,
                                         W_cls, b_cls, out);
}